// Round 8
// baseline (84.919 us; speedup 1.0000x reference)
//
#include <hip/hip_runtime.h>
#include <hip/hip_fp16.h>
#include <stdint.h>

typedef float f32x4 __attribute__((ext_vector_type(4)));
typedef _Float16 f16x8 __attribute__((ext_vector_type(8)));
typedef unsigned short us8 __attribute__((ext_vector_type(8)));
typedef unsigned long long u64t;

#define EPS  3.0e-3f

// ws layout (bytes)
#define WS_PCB   0         // ushort[65536] fp16 frag-linear codebook (128KB)
#define WS_CBT   131072    // float[65536] cb transposed [d][c] (256KB)
#define WS_C2    393216    // float[1024]
#define WS_SHARD 397312    // u32[16*1024] (64KB)
#define WS_ACT   462848    // int[1024]
#define WS_PART  466944    // float[512]
#define WS_DONE  468992    // u32[1]

__device__ __forceinline__ void gld16(const void* g, void* l) {
    __builtin_amdgcn_global_load_lds(
        (const __attribute__((address_space(1))) unsigned int*)g,
        (__attribute__((address_space(3))) unsigned int*)l,
        16, 0, 0);
}
__device__ __forceinline__ float hi_f(u64t v) {
    return __uint_as_float((unsigned)(v >> 32));
}

// ---------------- k0: init + fp16 frag-linear codebook + cbT + c2 ----------------
__global__ __launch_bounds__(256) void vq_k0(const float* __restrict__ cb,
                                             unsigned* __restrict__ shard,
                                             int* __restrict__ active,
                                             float* __restrict__ c2,
                                             unsigned short* __restrict__ pcb,
                                             float* __restrict__ cbT,
                                             unsigned* __restrict__ done) {
    int g = blockIdx.x * 256 + threadIdx.x;   // grid 64 -> 16384
    shard[g] = 0x7F800000u;                   // 16*1024 entries
    if (g == 0) done[0] = 0u;
    if (g < 1024) {
        active[g] = 0;
        const float4* row = (const float4*)(cb + g * 64);
        float s = 0.f;
#pragma unroll
        for (int q = 0; q < 16; ++q) {
            float4 v = row[q];
            s = fmaf(v.x, v.x, s); s = fmaf(v.y, v.y, s);
            s = fmaf(v.z, v.z, s); s = fmaf(v.w, v.w, s);
        }
        c2[g] = s;
    }
    if (g < 8192) {   // fp16 frag-linear: unit = (code c, 8-elem d-chunk u)
        int c = g >> 3, u = g & 7;
        const float4* row = (const float4*)(cb + c * 64);
        float4 v0 = row[u * 2], v1 = row[u * 2 + 1];
        us8 o;
        o[0] = __half_as_ushort(__float2half_rn(v0.x));
        o[1] = __half_as_ushort(__float2half_rn(v0.y));
        o[2] = __half_as_ushort(__float2half_rn(v0.z));
        o[3] = __half_as_ushort(__float2half_rn(v0.w));
        o[4] = __half_as_ushort(__float2half_rn(v1.x));
        o[5] = __half_as_ushort(__float2half_rn(v1.y));
        o[6] = __half_as_ushort(__float2half_rn(v1.z));
        o[7] = __half_as_ushort(__float2half_rn(v1.w));
        int frag  = (c >> 4) * 2 + (u >> 2);
        int lane8 = (c & 15) + 16 * (u & 3);
        *(us8*)&pcb[frag * 512 + lane8 * 8] = o;
    }
    {   // transpose: cbT[d][c] = cb[c][d]
        int c = g & 1023, seg = g >> 10;
        float4 v = ((const float4*)(cb + c * 64))[seg];
        cbT[(seg * 4 + 0) * 1024 + c] = v.x;
        cbT[(seg * 4 + 1) * 1024 + c] = v.y;
        cbT[(seg * 4 + 2) * 1024 + c] = v.z;
        cbT[(seg * 4 + 3) * 1024 + c] = v.w;
    }
}

// ---------------- k1: everything else ----------------
// grid 512 x 1024 thr (16 waves) -> 2 blocks/CU, 32 waves/CU.
// wave w: pg = w&3 (16-point group), q = w>>2 (code slice). B via LDS chunks of 256 codes.
__global__ __launch_bounds__(1024, 8) void vq_k1(const float* __restrict__ x,
                                                 const float* __restrict__ cb,
                                                 const float* __restrict__ c2g,
                                                 const unsigned short* __restrict__ pcb,
                                                 const float* __restrict__ cbT,
                                                 unsigned* __restrict__ shard,
                                                 int* __restrict__ active,
                                                 float* __restrict__ partial,
                                                 unsigned* __restrict__ done,
                                                 float* __restrict__ outp) {
    __shared__ __align__(16) unsigned short chunkB[16384];  // 32KB: 256-code fp16 chunk
    __shared__ __align__(16) unsigned short aF[4096];       // 8KB fp16 x-frags (64 pts)
    __shared__ float    c2s[1024];
    __shared__ unsigned mcode[1024];
    __shared__ float    x2s[64];
    __shared__ float    wd[4][64];
    __shared__ int      wc[4][64];
    __shared__ float    wm[4][64];
    __shared__ float    xl[64];
    __shared__ float    bdSh[64];
    __shared__ int      bcSh[64];
    __shared__ int      toksh[64];
    __shared__ int      flist[64];
    __shared__ unsigned nflag;
    __shared__ u64t     wmin[16];
    __shared__ int      lastSh;
    __shared__ double   red[1024];
    __shared__ double   entSh;

    const int tid  = threadIdx.x;
    const int lane = tid & 63;
    const int w    = tid >> 6;
    const int col  = lane & 15;
    const int rg   = lane >> 4;
    const int pg   = w & 3;
    const int q    = w >> 2;
    const int p0   = blockIdx.x * 64;

    // issue chunk-0 stage immediately (overlaps conversion VALU)
    {
        const char* src = (const char*)pcb + w * 2048 + (size_t)lane * 16;
        char* dst = (char*)chunkB + w * 2048 + lane * 16;
        gld16(src, dst);
        gld16(src + 1024, dst + 1024);
    }
    if (tid == 0) nflag = 0;

    // stage x -> fp16 frag-linear LDS + x2 (threads 0-255, verified r5-r7)
    if (tid < 256) {
        int r = tid >> 2, sg = tid & 3;
        const float4* xr4 = (const float4*)(x + (size_t)(p0 + r) * 64) + sg * 4;
        float4 v0 = xr4[0], v1 = xr4[1], v2 = xr4[2], v3 = xr4[3];
        float s = 0.f;
        s = fmaf(v0.x, v0.x, s); s = fmaf(v0.y, v0.y, s); s = fmaf(v0.z, v0.z, s); s = fmaf(v0.w, v0.w, s);
        s = fmaf(v1.x, v1.x, s); s = fmaf(v1.y, v1.y, s); s = fmaf(v1.z, v1.z, s); s = fmaf(v1.w, v1.w, s);
        s = fmaf(v2.x, v2.x, s); s = fmaf(v2.y, v2.y, s); s = fmaf(v2.z, v2.z, s); s = fmaf(v2.w, v2.w, s);
        s = fmaf(v3.x, v3.x, s); s = fmaf(v3.y, v3.y, s); s = fmaf(v3.z, v3.z, s); s = fmaf(v3.w, v3.w, s);
        s += __shfl_xor(s, 1);
        s += __shfl_xor(s, 2);
        if (sg == 0) x2s[r] = s;

        us8 o0, o1;
        o0[0]=__half_as_ushort(__float2half_rn(v0.x)); o0[1]=__half_as_ushort(__float2half_rn(v0.y));
        o0[2]=__half_as_ushort(__float2half_rn(v0.z)); o0[3]=__half_as_ushort(__float2half_rn(v0.w));
        o0[4]=__half_as_ushort(__float2half_rn(v1.x)); o0[5]=__half_as_ushort(__float2half_rn(v1.y));
        o0[6]=__half_as_ushort(__float2half_rn(v1.z)); o0[7]=__half_as_ushort(__float2half_rn(v1.w));
        o1[0]=__half_as_ushort(__float2half_rn(v2.x)); o1[1]=__half_as_ushort(__float2half_rn(v2.y));
        o1[2]=__half_as_ushort(__float2half_rn(v2.z)); o1[3]=__half_as_ushort(__float2half_rn(v2.w));
        o1[4]=__half_as_ushort(__float2half_rn(v3.x)); o1[5]=__half_as_ushort(__float2half_rn(v3.y));
        o1[6]=__half_as_ushort(__float2half_rn(v3.z)); o1[7]=__half_as_ushort(__float2half_rn(v3.w));
        int u0 = 2 * sg, u1 = 2 * sg + 1;
        int f0 = (r >> 4) * 2 + (u0 >> 2), l0 = (r & 15) + 16 * (u0 & 3);
        int f1 = (r >> 4) * 2 + (u1 >> 2), l1 = (r & 15) + 16 * (u1 & 3);
        *(us8*)&aF[f0 * 512 + l0 * 8] = o0;
        *(us8*)&aF[f1 * 512 + l1 * 8] = o1;
    }
    c2s[tid]   = c2g[tid];
    mcode[tid] = 0x7F800000u;
    __syncthreads();   // b1: aF/x2s/c2s/mcode ready; chunk-0 drained

    f16x8 a0 = *(const f16x8*)&aF[(pg * 2 + 0) * 512 + lane * 8];
    f16x8 a1 = *(const f16x8*)&aF[(pg * 2 + 1) * 512 + lane * 8];

    float x2r[4];
#pragma unroll
    for (int i = 0; i < 4; ++i) x2r[i] = x2s[pg * 16 + rg * 4 + i];

    float    m1d[4], m2r[4];
    unsigned m1c[4];
#pragma unroll
    for (int i = 0; i < 4; ++i) { m1d[i] = 3.4e38f; m2r[i] = 3.4e38f; m1c[i] = 0; }

    // main loop: 4 chunks x 4 tiles; all 16 waves share each LDS chunk
    for (int ch = 0; ch < 4; ++ch) {
#pragma unroll
        for (int t2 = 0; t2 < 4; ++t2) {
            const int fr = q * 4 + t2;                   // frag-pair within chunk
            f16x8 b0 = *(const f16x8*)&chunkB[(fr * 2 + 0) * 512 + lane * 8];
            f16x8 b1 = *(const f16x8*)&chunkB[(fr * 2 + 1) * 512 + lane * 8];
            f32x4 acc = (f32x4){0.f, 0.f, 0.f, 0.f};
            acc = __builtin_amdgcn_mfma_f32_16x16x32_f16(a0, b0, acc, 0, 0, 0);
            acc = __builtin_amdgcn_mfma_f32_16x16x32_f16(a1, b1, acc, 0, 0, 0);

            const int   cl  = ch * 256 + fr * 16 + col;  // global code (increasing per lane)
            const float c2v = c2s[cl];
            float fl[4];
#pragma unroll
            for (int i = 0; i < 4; ++i) {
                float dp = fmaf(-2.0f, acc[i], c2v);     // dist minus x2 (const per row)
                float lose = dp < m1d[i] ? m1d[i] : dp;
                m2r[i] = fminf(m2r[i], lose);
                m1c[i] = dp < m1d[i] ? (unsigned)cl : m1c[i];   // ties keep old (lower code)
                m1d[i] = fminf(m1d[i], dp);
                fl[i] = dp + x2r[i];
            }
            float pf = fminf(fminf(fl[0], fl[1]), fminf(fl[2], fl[3]));
            atomicMin(&mcode[cl], __float_as_uint(pf));  // LDS, no-return
        }
        if (ch < 3) {
            __syncthreads();   // chunk consumed by all waves
            const char* src = (const char*)pcb + (ch + 1) * 32768 + w * 2048 + (size_t)lane * 16;
            char* dst = (char*)chunkB + w * 2048 + lane * 16;
            gld16(src, dst);
            gld16(src + 1024, dst + 1024);
            __syncthreads();   // drained
        }
    }

    // butterfly across the 16 code-lanes (lexicographic)
#pragma unroll
    for (int s = 1; s < 16; s <<= 1) {
#pragma unroll
        for (int i = 0; i < 4; ++i) {
            float    od  = __shfl_xor(m1d[i], s);
            unsigned oc  = (unsigned)__shfl_xor((int)m1c[i], s);
            float    om2 = __shfl_xor(m2r[i], s);
            bool lt = (od < m1d[i]) || (od == m1d[i] && oc < m1c[i]);
            float lose = lt ? m1d[i] : od;
            m2r[i] = fminf(fminf(m2r[i], om2), lose);
            if (lt) { m1d[i] = od; m1c[i] = oc; }
        }
    }
    if (col == 0) {
#pragma unroll
        for (int i = 0; i < 4; ++i) {
            int pr = pg * 16 + rg * 4 + i;
            wd[q][pr] = m1d[i];
            wc[q][pr] = (int)m1c[i];
            wm[q][pr] = m2r[i];
        }
    }
    __syncthreads();   // b2: wd/wc/wm + mcode complete

    // threads 0-63: merge 4 slices (lexicographic: slices interleave code ranges)
    if (tid < 64) {
        float bd = wd[0][tid]; int bc = wc[0][tid]; float m2 = wm[0][tid];
#pragma unroll
        for (int qq = 1; qq < 4; ++qq) {
            float od = wd[qq][tid]; int oc = wc[qq][tid]; float om2 = wm[qq][tid];
            bool lt = (od < bd) || (od == bd && oc < bc);
            float lose = lt ? bd : od;
            m2 = fminf(fminf(m2, om2), lose);
            if (lt) { bd = od; bc = oc; }
        }
        bdSh[tid] = bd + x2s[tid];
        bcSh[tid] = bc;
        if (m2 - bd <= EPS) {                 // near-tie: exact in-block rescore
            unsigned ix = atomicAdd(&nflag, 1u);
            flist[ix] = tid;
        }
    }
    __syncthreads();   // flags final

    // exact fp32 rescore, block-wide: 1 thread = 1 code (reference-identical association)
    const unsigned nf = nflag;
    for (unsigned f = 0; f < nf; ++f) {
        const int pr = flist[f];
        if (tid < 64) xl[tid] = x[(size_t)(p0 + pr) * 64 + tid];
        __syncthreads();
        float x2v = 0.f;
#pragma unroll 8
        for (int d = 0; d < 64; ++d) x2v = fmaf(xl[d], xl[d], x2v);
        float s = 0.f;
        const float* ctp = cbT + tid;
#pragma unroll 8
        for (int d = 0; d < 64; ++d) s = fmaf(xl[d], ctp[d * 1024], s);
        float dist = (x2v - 2.f * s) + c2s[tid];
        u64t pk = ((u64t)__float_as_uint(dist) << 32) | (unsigned)tid;
#pragma unroll
        for (int m = 1; m < 64; m <<= 1) {
            u64t o = __shfl_xor(pk, m);
            if (o < pk) pk = o;
        }
        if (lane == 0) wmin[w] = pk;
        __syncthreads();
        if (tid < 16) {
            u64t v = wmin[tid];
#pragma unroll
            for (int m = 1; m < 16; m <<= 1) {
                u64t o = __shfl_xor(v, m);
                if (o < v) v = o;
            }
            if (tid == 0) { bdSh[pr] = hi_f(v); bcSh[pr] = (int)(unsigned)(v & 1023u); }
        }
        __syncthreads();
    }

    // finalize tokens/active + block partial loss-sum (deterministic shfl tree)
    if (tid < 64) {
        int bc = bcSh[tid];
        toksh[tid] = bc;
        atomicAdd(&active[bc], 1);
        float v = bdSh[tid];
        v += __shfl_xor(v, 1);  v += __shfl_xor(v, 2);  v += __shfl_xor(v, 4);
        v += __shfl_xor(v, 8);  v += __shfl_xor(v, 16); v += __shfl_xor(v, 32);
        if (tid == 0)
            __hip_atomic_store(&partial[blockIdx.x], v, __ATOMIC_RELEASE,
                               __HIP_MEMORY_SCOPE_AGENT);
    }
    // per-code min flush (sharded global atomics)
    atomicMin(&shard[(blockIdx.x & 15) * 1024 + tid], mcode[tid]);
    __syncthreads();   // b3: toksh ready

    // fused straight-through output: 1024 float4 (1/thread)
    {
        int g  = blockIdx.x * 1024 + tid;
        int pl = tid >> 4, qq = tid & 15;
        int tok = toksh[pl];
        float4 xv = ((const float4*)x)[g];
        float4 cv = ((const float4*)cb)[tok * 16 + qq];
        float4 o;
        o.x = xv.x + (cv.x - xv.x);
        o.y = xv.y + (cv.y - xv.y);
        o.z = xv.z + (cv.z - xv.z);
        o.w = xv.w + (cv.w - xv.w);
        ((float4*)outp)[g] = o;
    }

    // last-block: final loss (all cross-block data via device-scope atomics)
    __syncthreads();   // drains all memory ops (vmcnt 0) -> atomics performed
    if (tid == 0) {
        __threadfence();
        unsigned old = __hip_atomic_fetch_add(done, 1u, __ATOMIC_ACQ_REL,
                                              __HIP_MEMORY_SCOPE_AGENT);
        lastSh = (old == 511u);
    }
    __syncthreads();
    if (lastSh) {
        unsigned m = 0x7F800000u;
#pragma unroll
        for (int sI = 0; sI < 16; ++sI)
            m = min(m, __hip_atomic_load(&shard[sI * 1024 + tid], __ATOMIC_RELAXED,
                                         __HIP_MEMORY_SCOPE_AGENT));
        int act = __hip_atomic_load(&active[tid], __ATOMIC_RELAXED,
                                    __HIP_MEMORY_SCOPE_AGENT);
        red[tid] = (act == 0) ? (double)__uint_as_float(m) : 0.0;
        __syncthreads();
        for (int sI = 512; sI > 0; sI >>= 1) {
            if (tid < sI) red[tid] += red[tid + sI];
            __syncthreads();
        }
        if (tid == 0) entSh = red[0];
        __syncthreads();
        float pv = 0.f;
        if (tid < 512)
            pv = __hip_atomic_load(&partial[tid], __ATOMIC_RELAXED,
                                   __HIP_MEMORY_SCOPE_AGENT);
        red[tid] = (double)pv;
        __syncthreads();
        for (int sI = 512; sI > 0; sI >>= 1) {
            if (tid < sI) red[tid] += red[tid + sI];
            __syncthreads();
        }
        if (tid == 0) {
            double mean_sq = red[0] / (double)(32768ll * 64);
            double total = 1.25 * mean_sq + 0.01 * (entSh / 1024.0);
            outp[2097152] = (float)total;
        }
    }
}

extern "C" void kernel_launch(void* const* d_in, const int* in_sizes, int n_in,
                              void* d_out, int out_size, void* d_ws, size_t ws_size,
                              hipStream_t stream) {
    const float* x  = (const float*)d_in[0];
    const float* cb = (const float*)d_in[1];
    float* out = (float*)d_out;
    char* ws = (char*)d_ws;

    unsigned short* pcb     = (unsigned short*)(ws + WS_PCB);
    float*          cbT     = (float*)(ws + WS_CBT);
    float*          c2      = (float*)(ws + WS_C2);
    unsigned*       shard   = (unsigned*)(ws + WS_SHARD);
    int*            active  = (int*)(ws + WS_ACT);
    float*          partial = (float*)(ws + WS_PART);
    unsigned*       done    = (unsigned*)(ws + WS_DONE);

    vq_k0<<<64,   256, 0, stream>>>(cb, shard, active, c2, pcb, cbT, done);
    vq_k1<<<512, 1024, 0, stream>>>(x, cb, c2, pcb, cbT, shard, active,
                                    partial, done, out);
}

// Round 9
// 49.204 us; speedup vs baseline: 1.7259x; 1.7259x over previous
//
#include <hip/hip_runtime.h>
#include <hip/hip_fp16.h>
#include <stdint.h>

typedef float f32x4 __attribute__((ext_vector_type(4)));
typedef _Float16 f16x8 __attribute__((ext_vector_type(8)));
typedef unsigned short us8 __attribute__((ext_vector_type(8)));
typedef unsigned long long u64t;

#define EPS  3.0e-3f
#define FCAP 8192

// ws layout (bytes)
#define WS_TOKEN 0         // int[32768]
#define WS_BDIST 131072    // float[32768]
#define WS_PCB   262144    // ushort[65536] fp16 frag-linear codebook
#define WS_CBT   393216    // float[65536] cb transposed [d][c]
#define WS_C2    655360    // float[1024]
#define WS_SHARD 659456    // u32[16*1024]
#define WS_ACT   724992    // int[1024]
#define WS_FLAG  729088    // int[8192]
#define WS_FCNT  761856    // u32[64]

__device__ __forceinline__ void gld16(const void* g, void* l) {
    __builtin_amdgcn_global_load_lds(
        (const __attribute__((address_space(1))) unsigned int*)g,
        (__attribute__((address_space(3))) unsigned int*)l,
        16, 0, 0);
}
__device__ __forceinline__ float hi_f(u64t v) {
    return __uint_as_float((unsigned)(v >> 32));
}

// ---------------- k0: init + fp16 frag-linear codebook + cbT + c2 ----------------
__global__ __launch_bounds__(256) void vq_k0(const float* __restrict__ cb,
                                             unsigned* __restrict__ shard,
                                             int* __restrict__ active,
                                             float* __restrict__ c2,
                                             unsigned short* __restrict__ pcb,
                                             float* __restrict__ cbT,
                                             unsigned* __restrict__ fcnt) {
    int g = blockIdx.x * 256 + threadIdx.x;   // grid 64 -> 16384
    shard[g] = 0x7F800000u;                   // 16*1024 entries
    if (g < 64) fcnt[g] = 0;
    if (g < 1024) {
        active[g] = 0;
        const float4* row = (const float4*)(cb + g * 64);
        float s = 0.f;
#pragma unroll
        for (int q = 0; q < 16; ++q) {
            float4 v = row[q];
            s = fmaf(v.x, v.x, s); s = fmaf(v.y, v.y, s);
            s = fmaf(v.z, v.z, s); s = fmaf(v.w, v.w, s);
        }
        c2[g] = s;
    }
    if (g < 8192) {   // fp16 frag-linear: unit = (code c, 8-elem d-chunk u)
        int c = g >> 3, u = g & 7;
        const float4* row = (const float4*)(cb + c * 64);
        float4 v0 = row[u * 2], v1 = row[u * 2 + 1];
        us8 o;
        o[0] = __half_as_ushort(__float2half_rn(v0.x));
        o[1] = __half_as_ushort(__float2half_rn(v0.y));
        o[2] = __half_as_ushort(__float2half_rn(v0.z));
        o[3] = __half_as_ushort(__float2half_rn(v0.w));
        o[4] = __half_as_ushort(__float2half_rn(v1.x));
        o[5] = __half_as_ushort(__float2half_rn(v1.y));
        o[6] = __half_as_ushort(__float2half_rn(v1.z));
        o[7] = __half_as_ushort(__float2half_rn(v1.w));
        int frag  = (c >> 4) * 2 + (u >> 2);
        int lane8 = (c & 15) + 16 * (u & 3);
        *(us8*)&pcb[frag * 512 + lane8 * 8] = o;
    }
    {   // transpose: cbT[d][c] = cb[c][d]
        int c = g & 1023, seg = g >> 10;
        float4 v = ((const float4*)(cb + c * 64))[seg];
        cbT[(seg * 4 + 0) * 1024 + c] = v.x;
        cbT[(seg * 4 + 1) * 1024 + c] = v.y;
        cbT[(seg * 4 + 2) * 1024 + c] = v.z;
        cbT[(seg * 4 + 3) * 1024 + c] = v.w;
    }
}

// ---------------- k1: 1024-thr block, 64 pts x full codebook; B double-buffered
//                      through LDS (8 chunks x 128 codes); fused ST output ----------------
// grid 512 -> 2 blocks/CU -> 32 waves/CU. wave (pg = w&3: 16 pts, q = w>>2: code slice).
__global__ __launch_bounds__(1024, 8) void vq_k1(const float* __restrict__ x,
                                                 const float* __restrict__ cb,
                                                 const float* __restrict__ c2g,
                                                 const unsigned short* __restrict__ pcb,
                                                 unsigned* __restrict__ shard,
                                                 int* __restrict__ token,
                                                 float* __restrict__ bdist,
                                                 int* __restrict__ active,
                                                 int* __restrict__ gflag,
                                                 unsigned* __restrict__ fcnt,
                                                 float* __restrict__ outp) {
    __shared__ __align__(16) unsigned short chunkB[2][8192];  // 2x16KB: 128-code fp16 chunks
    __shared__ __align__(16) unsigned short aF[4096];         // 8KB fp16 x-frags (64 pts)
    __shared__ float    c2s[1024];
    __shared__ unsigned mcode[1024];
    __shared__ float    x2s[64];
    __shared__ float    wd[4][64];
    __shared__ int      wc[4][64];
    __shared__ float    wm[4][64];
    __shared__ int      toksh[64];

    const int tid  = threadIdx.x;
    const int lane = tid & 63;
    const int w    = tid >> 6;
    const int col  = lane & 15;
    const int rg   = lane >> 4;
    const int pg   = w & 3;        // point group (16 pts)
    const int q    = w >> 2;       // code slice within each chunk
    const int p0   = blockIdx.x * 64;

    // issue chunk-0 stage immediately (overlaps conversion VALU)
    gld16((const char*)pcb + w * 1024 + (size_t)lane * 16,
          (char*)&chunkB[0][0] + w * 1024 + lane * 16);

    // stage x -> fp16 frag-linear LDS + x2 (threads 0-255, verified r5-r7)
    if (tid < 256) {
        int r = tid >> 2, sg = tid & 3;
        const float4* xr4 = (const float4*)(x + (size_t)(p0 + r) * 64) + sg * 4;
        float4 v0 = xr4[0], v1 = xr4[1], v2 = xr4[2], v3 = xr4[3];
        float s = 0.f;
        s = fmaf(v0.x, v0.x, s); s = fmaf(v0.y, v0.y, s); s = fmaf(v0.z, v0.z, s); s = fmaf(v0.w, v0.w, s);
        s = fmaf(v1.x, v1.x, s); s = fmaf(v1.y, v1.y, s); s = fmaf(v1.z, v1.z, s); s = fmaf(v1.w, v1.w, s);
        s = fmaf(v2.x, v2.x, s); s = fmaf(v2.y, v2.y, s); s = fmaf(v2.z, v2.z, s); s = fmaf(v2.w, v2.w, s);
        s = fmaf(v3.x, v3.x, s); s = fmaf(v3.y, v3.y, s); s = fmaf(v3.z, v3.z, s); s = fmaf(v3.w, v3.w, s);
        s += __shfl_xor(s, 1);
        s += __shfl_xor(s, 2);
        if (sg == 0) x2s[r] = s;

        us8 o0, o1;
        o0[0]=__half_as_ushort(__float2half_rn(v0.x)); o0[1]=__half_as_ushort(__float2half_rn(v0.y));
        o0[2]=__half_as_ushort(__float2half_rn(v0.z)); o0[3]=__half_as_ushort(__float2half_rn(v0.w));
        o0[4]=__half_as_ushort(__float2half_rn(v1.x)); o0[5]=__half_as_ushort(__float2half_rn(v1.y));
        o0[6]=__half_as_ushort(__float2half_rn(v1.z)); o0[7]=__half_as_ushort(__float2half_rn(v1.w));
        o1[0]=__half_as_ushort(__float2half_rn(v2.x)); o1[1]=__half_as_ushort(__float2half_rn(v2.y));
        o1[2]=__half_as_ushort(__float2half_rn(v2.z)); o1[3]=__half_as_ushort(__float2half_rn(v2.w));
        o1[4]=__half_as_ushort(__float2half_rn(v3.x)); o1[5]=__half_as_ushort(__float2half_rn(v3.y));
        o1[6]=__half_as_ushort(__float2half_rn(v3.z)); o1[7]=__half_as_ushort(__float2half_rn(v3.w));
        int u0 = 2 * sg, u1 = 2 * sg + 1;
        int f0 = (r >> 4) * 2 + (u0 >> 2), l0 = (r & 15) + 16 * (u0 & 3);
        int f1 = (r >> 4) * 2 + (u1 >> 2), l1 = (r & 15) + 16 * (u1 & 3);
        *(us8*)&aF[f0 * 512 + l0 * 8] = o0;
        *(us8*)&aF[f1 * 512 + l1 * 8] = o1;
    }
    c2s[tid]   = c2g[tid];
    mcode[tid] = 0x7F800000u;
    __syncthreads();   // b1: aF/x2s/c2s/mcode ready; chunk-0 drained (vmcnt 0 at barrier)

    f16x8 a0 = *(const f16x8*)&aF[(pg * 2 + 0) * 512 + lane * 8];
    f16x8 a1 = *(const f16x8*)&aF[(pg * 2 + 1) * 512 + lane * 8];

    float x2r[4];
#pragma unroll
    for (int i = 0; i < 4; ++i) x2r[i] = x2s[pg * 16 + rg * 4 + i];

    float    m1d[4], m2r[4];
    unsigned m1c[4];
#pragma unroll
    for (int i = 0; i < 4; ++i) { m1d[i] = 3.4e38f; m2r[i] = 3.4e38f; m1c[i] = 0; }

    // main loop: 8 chunks of 128 codes, double-buffered; wave q does 2 tiles/chunk
    int cur = 0;
    for (int ch = 0; ch < 8; ++ch) {
        if (ch < 7)   // prefetch next chunk into the other buffer (everyone done with it)
            gld16((const char*)pcb + (ch + 1) * 16384 + w * 1024 + (size_t)lane * 16,
                  (char*)&chunkB[cur ^ 1][0] + w * 1024 + lane * 16);

#pragma unroll
        for (int t2 = 0; t2 < 2; ++t2) {
            const int lf = q * 2 + t2;                   // local code-tile in chunk
            f16x8 b0 = *(const f16x8*)&chunkB[cur][(lf * 2 + 0) * 512 + lane * 8];
            f16x8 b1 = *(const f16x8*)&chunkB[cur][(lf * 2 + 1) * 512 + lane * 8];
            f32x4 acc = (f32x4){0.f, 0.f, 0.f, 0.f};
            acc = __builtin_amdgcn_mfma_f32_16x16x32_f16(a0, b0, acc, 0, 0, 0);
            acc = __builtin_amdgcn_mfma_f32_16x16x32_f16(a1, b1, acc, 0, 0, 0);

            const int   cl  = ch * 128 + lf * 16 + col;  // global code (increasing per lane)
            const float c2v = c2s[cl];
            float fl[4];
#pragma unroll
            for (int i = 0; i < 4; ++i) {
                float dp = fmaf(-2.0f, acc[i], c2v);     // dist minus x2 (const per row)
                float lose = dp < m1d[i] ? m1d[i] : dp;
                m2r[i] = fminf(m2r[i], lose);
                m1c[i] = dp < m1d[i] ? (unsigned)cl : m1c[i];   // ties keep old (lower code)
                m1d[i] = fminf(m1d[i], dp);
                fl[i] = dp + x2r[i];
            }
            float pf = fminf(fminf(fl[0], fl[1]), fminf(fl[2], fl[3]));
            atomicMin(&mcode[cl], __float_as_uint(pf));  // LDS, no-return
        }
        __syncthreads();   // all reads of chunk[cur] done; prefetch drained
        cur ^= 1;
    }

    // butterfly across the 16 code-lanes (lexicographic, first-index tie-break)
#pragma unroll
    for (int s = 1; s < 16; s <<= 1) {
#pragma unroll
        for (int i = 0; i < 4; ++i) {
            float    od  = __shfl_xor(m1d[i], s);
            unsigned oc  = (unsigned)__shfl_xor((int)m1c[i], s);
            float    om2 = __shfl_xor(m2r[i], s);
            bool lt = (od < m1d[i]) || (od == m1d[i] && oc < m1c[i]);
            float lose = lt ? m1d[i] : od;
            m2r[i] = fminf(fminf(m2r[i], om2), lose);
            if (lt) { m1d[i] = od; m1c[i] = oc; }
        }
    }
    if (col == 0) {
#pragma unroll
        for (int i = 0; i < 4; ++i) {
            int pr = pg * 16 + rg * 4 + i;
            wd[q][pr] = m1d[i];
            wc[q][pr] = (int)m1c[i];
            wm[q][pr] = m2r[i];
        }
    }
    __syncthreads();   // b2: wd/wc/wm + mcode complete

    // threads 0-63: merge 4 slices (lexicographic: slices interleave code ranges)
    if (tid < 64) {
        float bd = wd[0][tid]; int bc = wc[0][tid]; float m2 = wm[0][tid];
#pragma unroll
        for (int qq = 1; qq < 4; ++qq) {
            float od = wd[qq][tid]; int oc = wc[qq][tid]; float om2 = wm[qq][tid];
            bool lt = (od < bd) || (od == bd && oc < bc);
            float lose = lt ? bd : od;
            m2 = fminf(fminf(m2, om2), lose);
            if (lt) { bd = od; bc = oc; }
        }
        int p = p0 + tid;
        token[p]   = bc;
        toksh[tid] = bc;
        bdist[p]   = bd + x2s[tid];
        atomicAdd(&active[bc], 1);
        if (m2 - bd <= EPS) {                 // near-tie: exact resolution needed
            unsigned ix = atomicAdd(fcnt, 1u);
            if (ix < FCAP) gflag[ix] = p;
        }
    }
    {   // flush block per-code mins to sharded global (1 atomic/thread)
        atomicMin(&shard[(blockIdx.x & 15) * 1024 + tid], mcode[tid]);
    }
    __syncthreads();   // b3: toksh ready

    // fused straight-through output: 64 pts x 16 float4 = 1024 float4 (1/thread)
    {
        int g  = blockIdx.x * 1024 + tid;     // global float4 index
        int pl = tid >> 4, qq = tid & 15;
        int tok = toksh[pl];
        float4 xv = ((const float4*)x)[g];
        float4 cv = ((const float4*)cb)[tok * 16 + qq];
        float4 o;
        o.x = xv.x + (cv.x - xv.x);
        o.y = xv.y + (cv.y - xv.y);
        o.z = xv.z + (cv.z - xv.z);
        o.w = xv.w + (cv.w - xv.w);
        ((float4*)outp)[g] = o;
    }
}

// ---------------- kfix: exact fp32 rescan for flagged points (+fix out/active) ----------------
__global__ __launch_bounds__(256) void vq_kfix(const float* __restrict__ x,
                                               const float* __restrict__ cb,
                                               const float* __restrict__ cbT,
                                               const float* __restrict__ c2,
                                               const int* __restrict__ gflag,
                                               const unsigned* __restrict__ fcnt,
                                               int* __restrict__ token,
                                               float* __restrict__ bdist,
                                               int* __restrict__ active,
                                               float* __restrict__ outp) {
    __shared__ float xl[64];
    __shared__ u64t red[256];
    __shared__ u64t bestSh;
    const int tid = threadIdx.x;
    unsigned nf = fcnt[0]; if (nf > FCAP) nf = FCAP;

    for (unsigned fi = blockIdx.x; fi < nf; fi += gridDim.x) {   // grid 256
        int p = gflag[fi];
        __syncthreads();
        if (tid < 64) xl[tid] = x[(size_t)p * 64 + tid];
        __syncthreads();
        float x2v = 0.f;   // exact x2: sequential fma, reference association
#pragma unroll
        for (int d = 0; d < 64; ++d) x2v = fmaf(xl[d], xl[d], x2v);
        float s0 = 0.f, s1 = 0.f, s2 = 0.f, s3 = 0.f;
#pragma unroll
        for (int d = 0; d < 64; ++d) {
            float xv = xl[d];
            s0 = fmaf(xv, cbT[d * 1024 +   0 + tid], s0);
            s1 = fmaf(xv, cbT[d * 1024 + 256 + tid], s1);
            s2 = fmaf(xv, cbT[d * 1024 + 512 + tid], s2);
            s3 = fmaf(xv, cbT[d * 1024 + 768 + tid], s3);
        }
        float d0 = (x2v - 2.f * s0) + c2[tid];
        float d1 = (x2v - 2.f * s1) + c2[tid + 256];
        float d2 = (x2v - 2.f * s2) + c2[tid + 512];
        float d3 = (x2v - 2.f * s3) + c2[tid + 768];
        u64t bb = ~0ull, pk;
        pk = ((u64t)__float_as_uint(d0) << 32) | (unsigned)(tid);       if (pk < bb) bb = pk;
        pk = ((u64t)__float_as_uint(d1) << 32) | (unsigned)(tid + 256); if (pk < bb) bb = pk;
        pk = ((u64t)__float_as_uint(d2) << 32) | (unsigned)(tid + 512); if (pk < bb) bb = pk;
        pk = ((u64t)__float_as_uint(d3) << 32) | (unsigned)(tid + 768); if (pk < bb) bb = pk;
        red[tid] = bb;
        __syncthreads();
        for (int s = 128; s > 0; s >>= 1) {
            if (tid < s) { u64t o = red[tid + s]; if (o < red[tid]) red[tid] = o; }
            __syncthreads();
        }
        if (tid == 0) {
            u64t b = red[0];
            bestSh = b;
            int newc = (int)(unsigned)(b & 0xFFFFFFFFu);
            int oldc = token[p];
            token[p] = newc;
            bdist[p] = hi_f(b);
            if (newc != oldc) {
                atomicAdd(&active[oldc], -1);
                atomicAdd(&active[newc], 1);
            }
        }
        __syncthreads();
        int newc = (int)(unsigned)(bestSh & 0xFFFFFFFFu);
        if (tid < 64) {   // patch the output row
            float xv = xl[tid];
            float cv = cb[(size_t)newc * 64 + tid];
            outp[(size_t)p * 64 + tid] = xv + (cv - xv);
        }
    }
}

// ---------------- k3f: shard merge + entropy + bdist sum + final loss ----------------
__global__ __launch_bounds__(1024) void vq_k3f(const unsigned* __restrict__ shard,
                                               const int* __restrict__ active,
                                               const float* __restrict__ bdist,
                                               float* __restrict__ out_loss) {
    __shared__ double red[1024];
    __shared__ double entS;
    const int t = threadIdx.x;

    unsigned m = 0x7F800000u;
#pragma unroll
    for (int s = 0; s < 16; ++s) m = min(m, shard[s * 1024 + t]);
    red[t] = (active[t] == 0) ? (double)__uint_as_float(m) : 0.0;
    __syncthreads();
    for (int s = 512; s > 0; s >>= 1) {
        if (t < s) red[t] += red[t + s];
        __syncthreads();
    }
    if (t == 0) entS = red[0];
    __syncthreads();

    double acc = 0.0;
#pragma unroll
    for (int k = 0; k < 32; ++k) acc += (double)bdist[k * 1024 + t];
    red[t] = acc;
    __syncthreads();
    for (int s = 512; s > 0; s >>= 1) {
        if (t < s) red[t] += red[t + s];
        __syncthreads();
    }
    if (t == 0) {
        double mean_sq = red[0] / (double)(32768ll * 64);
        double total = 1.25 * mean_sq + 0.01 * (entS / 1024.0);
        out_loss[0] = (float)total;
    }
}

extern "C" void kernel_launch(void* const* d_in, const int* in_sizes, int n_in,
                              void* d_out, int out_size, void* d_ws, size_t ws_size,
                              hipStream_t stream) {
    const float* x  = (const float*)d_in[0];
    const float* cb = (const float*)d_in[1];
    float* out = (float*)d_out;
    char* ws = (char*)d_ws;

    int*            token  = (int*)(ws + WS_TOKEN);
    float*          bdist  = (float*)(ws + WS_BDIST);
    unsigned short* pcb    = (unsigned short*)(ws + WS_PCB);
    float*          cbT    = (float*)(ws + WS_CBT);
    float*          c2     = (float*)(ws + WS_C2);
    unsigned*       shard  = (unsigned*)(ws + WS_SHARD);
    int*            active = (int*)(ws + WS_ACT);
    int*            gflag  = (int*)(ws + WS_FLAG);
    unsigned*       fcnt   = (unsigned*)(ws + WS_FCNT);

    vq_k0  <<<64,   256, 0, stream>>>(cb, shard, active, c2, pcb, cbT, fcnt);
    vq_k1  <<<512, 1024, 0, stream>>>(x, cb, c2, pcb, shard, token, bdist,
                                      active, gflag, fcnt, out);
    vq_kfix<<<256,  256, 0, stream>>>(x, cb, cbT, c2, gflag, fcnt, token, bdist,
                                      active, out);
    vq_k3f <<<1,   1024, 0, stream>>>(shard, active, bdist, out + 2097152);
}